// Round 1
// baseline (375.293 us; speedup 1.0000x reference)
//
#include <hip/hip_runtime.h>
#include <hip/hip_bf16.h>

#define TT 512
#define DD 512
#define VV 2048
#define HH 128

typedef __attribute__((ext_vector_type(8))) short bf16x8;
typedef __attribute__((ext_vector_type(8))) unsigned short ushort8;
typedef __attribute__((ext_vector_type(4))) unsigned short ushort4v;
typedef __attribute__((ext_vector_type(4))) float f32x4;

__device__ __forceinline__ unsigned short f2bf(float f) {
  union { __hip_bfloat16 b; unsigned short u; } cv;
  cv.b = __float2bfloat16(f);
  return cv.u;
}

// Pre-pass: convert video embeddings fp32 -> bf16 once (shared by all voxels).
__global__ void cvt_x_kernel(const float* __restrict__ x, unsigned short* __restrict__ xb) {
  const int i = blockIdx.x * blockDim.x + threadIdx.x;   // 65536 threads x 4 elems
  const float4 f = ((const float4*)x)[i];
  ushort4v u;
  u[0] = f2bf(f.x); u[1] = f2bf(f.y); u[2] = f2bf(f.z); u[3] = f2bf(f.w);
  ((ushort4v*)xb)[i] = u;
}

// One workgroup per voxel. 512 threads = 8 waves; wave w owns t-rows [w*64, w*64+64).
// LDS map (64 KiB):
//   [0, 32768)      : W2[v] bf16, fragment-linear, 4 k-tiles of 8 KiB
//   [32768, 49152)  : W1 k-tile double buffer (2 x 8 KiB), fragment-linear   (phase A)
//   [32768, 65536)  : per-wave h1 slots, 8 x 4 KiB, XOR-swizzled [16t][128h] (phase B)
__global__ __launch_bounds__(512, 2)
void voxel_mlp_kernel(const unsigned short* __restrict__ Xb,
                      const float* __restrict__ W1,
                      const float* __restrict__ b1,
                      const float* __restrict__ W2,
                      const float* __restrict__ b2,
                      const float* __restrict__ W3,
                      const float* __restrict__ b3,
                      float* __restrict__ out) {
  __shared__ __align__(16) char LDS[65536];
  constexpr unsigned W2BASE = 0;
  constexpr unsigned R1     = 32768;
  constexpr unsigned H1BASE = 32768;

  const int v   = blockIdx.x;
  const int tid = threadIdx.x;
  const int w   = tid >> 6;
  const int l   = tid & 63;
  const int lg  = l >> 4;   // 16-lane group 0..3
  const int ll  = l & 15;

  const float* W1v = W1 + (size_t)v * DD * HH;
  const float* W2v = W2 + (size_t)v * HH * HH;

  // ---- prologue: stage W1 k-tile 0 into buffer 0 ----
  {
    const float* gp = W1v + (lg * 8) * HH + w * 16 + ll;
    float f[8];
#pragma unroll
    for (int j = 0; j < 8; ++j) f[j] = gp[j * HH];
    ushort8 u;
#pragma unroll
    for (int j = 0; j < 8; ++j) u[j] = f2bf(f[j]);
    *(ushort8*)(&LDS[R1 + (unsigned)w * 1024u + (unsigned)l * 16u]) = u;
  }
  __syncthreads();

  f32x4 acc1[4][8];
#pragma unroll
  for (int mi = 0; mi < 4; ++mi)
#pragma unroll
    for (int n = 0; n < 8; ++n) acc1[mi][n] = f32x4{0.f, 0.f, 0.f, 0.f};

  // ---- phase A: layer 1, K-loop over D in steps of 32 ----
#pragma unroll
  for (int step = 0; step < 16; ++step) {
    const int dk = step * 32;
    const unsigned buf = R1 + (unsigned)(step & 1) * 8192u;

    // issue next-tile staging loads early (hide HBM latency under MFMAs)
    float s1[8];
    if (step < 15) {
      const float* gp = W1v + (dk + 32 + lg * 8) * HH + w * 16 + ll;
#pragma unroll
      for (int j = 0; j < 8; ++j) s1[j] = gp[j * HH];
    }
    float s2[8];
    if (step >= 1 && step <= 4) {
      const float* gp = W2v + ((step - 1) * 32 + lg * 8) * HH + w * 16 + ll;
#pragma unroll
      for (int j = 0; j < 8; ++j) s2[j] = gp[j * HH];
    }

    // A-fragments straight from global bf16 X (L2-resident, 16 B/lane)
    bf16x8 a[4];
#pragma unroll
    for (int mi = 0; mi < 4; ++mi)
      a[mi] = *(const bf16x8*)(Xb + (size_t)(w * 64 + mi * 16 + ll) * DD + dk + lg * 8);

    // B-fragments: fragment-linear LDS -> one conflict-free ds_read_b128 each
    bf16x8 b[8];
#pragma unroll
    for (int n = 0; n < 8; ++n)
      b[n] = *(const bf16x8*)(&LDS[buf + (unsigned)n * 1024u + (unsigned)l * 16u]);

#pragma unroll
    for (int n = 0; n < 8; ++n)
#pragma unroll
      for (int mi = 0; mi < 4; ++mi)
        acc1[mi][n] = __builtin_amdgcn_mfma_f32_16x16x32_bf16(a[mi], b[n], acc1[mi][n], 0, 0, 0);

    // staging writes (convert + fragment-linear scatter)
    if (step < 15) {
      ushort8 u;
#pragma unroll
      for (int j = 0; j < 8; ++j) u[j] = f2bf(s1[j]);
      *(ushort8*)(&LDS[R1 + (unsigned)((step + 1) & 1) * 8192u + (unsigned)w * 1024u + (unsigned)l * 16u]) = u;
    }
    if (step >= 1 && step <= 4) {
      ushort8 u;
#pragma unroll
      for (int j = 0; j < 8; ++j) u[j] = f2bf(s2[j]);
      *(ushort8*)(&LDS[W2BASE + (unsigned)(step - 1) * 8192u + (unsigned)w * 1024u + (unsigned)l * 16u]) = u;
    }
    __syncthreads();
  }

  // per-lane biases / head weights (fp32, kept exact)
  float b1v[8], b2v[8], w3v[8];
#pragma unroll
  for (int n = 0; n < 8; ++n) {
    b1v[n] = b1[v * HH + n * 16 + ll];
    b2v[n] = b2[v * HH + n * 16 + ll];
    w3v[n] = W3[v * HH + n * 16 + ll];
  }
  const float b3v = b3[v];

  const unsigned slot = H1BASE + (unsigned)w * 4096u;  // wave-private 16x128 bf16

  // ---- phase B: layers 2+3, per 16-row block (no cross-wave sync needed) ----
#pragma unroll
  for (int mi = 0; mi < 4; ++mi) {
    // write h1 block, XOR-swizzle rows so layer-2 A-frag reads are conflict-free
#pragma unroll
    for (int n = 0; n < 8; ++n) {
#pragma unroll
      for (int r = 0; r < 4; ++r) {
        const int tl = lg * 4 + r;                       // C-layout row
        float hv = acc1[mi][n][r] + b1v[n];
        hv = fmaxf(hv, 0.f);
        const int h = n * 16 + ll;                       // C-layout col
        const unsigned byte = slot + (unsigned)tl * 256u + (unsigned)((h * 2) ^ ((tl & 7) << 4));
        *(unsigned short*)(&LDS[byte]) = f2bf(hv);
      }
    }
    // layer 2: [16t x 128h] = h1 @ W2
    f32x4 acc2[8];
#pragma unroll
    for (int n = 0; n < 8; ++n) acc2[n] = f32x4{0.f, 0.f, 0.f, 0.f};
#pragma unroll
    for (int ki = 0; ki < 4; ++ki) {
      const int k0 = ki * 32 + lg * 8;
      const unsigned abyte = slot + (unsigned)ll * 256u + (unsigned)((k0 * 2) ^ ((ll & 7) << 4));
      const bf16x8 a2 = *(const bf16x8*)(&LDS[abyte]);
#pragma unroll
      for (int n = 0; n < 8; ++n) {
        const bf16x8 bw = *(const bf16x8*)(&LDS[W2BASE + (unsigned)ki * 8192u + (unsigned)n * 1024u + (unsigned)l * 16u]);
        acc2[n] = __builtin_amdgcn_mfma_f32_16x16x32_bf16(a2, bw, acc2[n], 0, 0, 0);
      }
    }
    // layer 3 (fp32): relu(acc2+b2) . w3, 16-lane butterfly reduce, lane0 writes
#pragma unroll
    for (int r = 0; r < 4; ++r) {
      float p = 0.f;
#pragma unroll
      for (int n = 0; n < 8; ++n)
        p += fmaxf(acc2[n][r] + b2v[n], 0.f) * w3v[n];
      p += __shfl_xor(p, 1);
      p += __shfl_xor(p, 2);
      p += __shfl_xor(p, 4);
      p += __shfl_xor(p, 8);
      if (ll == 0) {
        const int t = w * 64 + mi * 16 + lg * 4 + r;
        out[t * VV + v] = p + b3v;
      }
    }
  }
}

extern "C" void kernel_launch(void* const* d_in, const int* in_sizes, int n_in,
                              void* d_out, int out_size, void* d_ws, size_t ws_size,
                              hipStream_t stream) {
  const float* X  = (const float*)d_in[0];
  const float* W1 = (const float*)d_in[1];
  const float* b1 = (const float*)d_in[2];
  const float* W2 = (const float*)d_in[3];
  const float* b2 = (const float*)d_in[4];
  const float* W3 = (const float*)d_in[5];
  const float* b3 = (const float*)d_in[6];
  float* out = (float*)d_out;

  unsigned short* Xb = (unsigned short*)d_ws;   // 512 KiB bf16 X

  cvt_x_kernel<<<256, 256, 0, stream>>>(X, Xb);
  voxel_mlp_kernel<<<VV, 512, 0, stream>>>(Xb, W1, b1, W2, b2, W3, b3, out);
}

// Round 2
// 298.384 us; speedup vs baseline: 1.2578x; 1.2578x over previous
//
#include <hip/hip_runtime.h>
#include <hip/hip_bf16.h>

#define TT 512
#define DD 512
#define VV 2048
#define HH 128

typedef __attribute__((ext_vector_type(8))) short bf16x8;
typedef __attribute__((ext_vector_type(8))) unsigned short ushort8;
typedef __attribute__((ext_vector_type(4))) unsigned short ushort4v;
typedef __attribute__((ext_vector_type(4))) float f32x4;

__device__ __forceinline__ unsigned short f2bf(float f) {
  union { __hip_bfloat16 b; unsigned short u; } cv;
  cv.b = __float2bfloat16(f);
  return cv.u;
}

// Pre-pass: convert video embeddings fp32 -> bf16 once (shared by all voxels).
__global__ void cvt_x_kernel(const float* __restrict__ x, unsigned short* __restrict__ xb) {
  const int i = blockIdx.x * blockDim.x + threadIdx.x;
  const float4 f = ((const float4*)x)[i];
  ushort4v u;
  u[0] = f2bf(f.x); u[1] = f2bf(f.y); u[2] = f2bf(f.z); u[3] = f2bf(f.w);
  ((ushort4v*)xb)[i] = u;
}

// One workgroup per voxel. 512 threads = 8 waves; wave w owns t-rows [w*64, w*64+64).
// LDS map (64 KiB):
//   [0, 32768)      : W2[v] bf16, fragment-linear, 4 k-tiles of 8 KiB
//   [32768, 65536)  : W1 k-tile RING x4 (8 KiB each), fragment-linear   (phase A)
//   [32768, 65536)  : per-wave h1 slots, 8 x 4 KiB, XOR-swizzled        (phase B)
__global__ __launch_bounds__(512, 2)
void voxel_mlp_kernel(const unsigned short* __restrict__ Xb,
                      const float* __restrict__ W1,
                      const float* __restrict__ b1,
                      const float* __restrict__ W2,
                      const float* __restrict__ b2,
                      const float* __restrict__ W3,
                      const float* __restrict__ b3,
                      float* __restrict__ out) {
  __shared__ __align__(16) char LDS[65536];
  constexpr unsigned W2BASE = 0;
  constexpr unsigned R1     = 32768;
  constexpr unsigned H1BASE = 32768;

  const int v   = blockIdx.x;
  const int tid = threadIdx.x;
  const int w   = tid >> 6;
  const int l   = tid & 63;
  const int lg  = l >> 4;
  const int ll  = l & 15;

  const float* W1v = W1 + (size_t)v * DD * HH;
  const float* W2v = W2 + (size_t)v * HH * HH;

  // per-lane staging source offset within a 32-row tile (fp32 elements)
  const int stago = (lg * 8) * HH + w * 16 + ll;
  // per-lane A-fragment base (bf16 elements): row block for this wave
  const unsigned short* Xrow[4];
#pragma unroll
  for (int mi = 0; mi < 4; ++mi)
    Xrow[mi] = Xb + (size_t)(w * 64 + mi * 16 + ll) * DD + lg * 8;

  // prefetch register slots (statically indexed under full unroll)
  float w1s[4][8];
  float w2s[2][8];
  bf16x8 aS[2][4];

#define ISSUE_W1(t, slot)                                         \
  { const float* gp = W1v + stago + (t) * 32 * HH;                \
    _Pragma("unroll") for (int j = 0; j < 8; ++j)                 \
      w1s[slot][j] = gp[j * HH]; }

#define ISSUE_W2(t, slot)                                         \
  { const float* gp = W2v + stago + (t) * 32 * HH;                \
    _Pragma("unroll") for (int j = 0; j < 8; ++j)                 \
      w2s[slot][j] = gp[j * HH]; }

#define ISSUE_A(st, slot)                                         \
  { _Pragma("unroll") for (int mi = 0; mi < 4; ++mi)              \
      aS[slot][mi] = *(const bf16x8*)(Xrow[mi] + (st) * 32); }

#define CVT_W1(slot, dstByte)                                     \
  { ushort8 u;                                                    \
    _Pragma("unroll") for (int j = 0; j < 8; ++j)                 \
      u[j] = f2bf(w1s[slot][j]);                                  \
    *(ushort8*)(&LDS[(dstByte) + (unsigned)w * 1024u + (unsigned)l * 16u]) = u; }

#define CVT_W2(slot, dstByte)                                     \
  { ushort8 u;                                                    \
    _Pragma("unroll") for (int j = 0; j < 8; ++j)                 \
      u[j] = f2bf(w2s[slot][j]);                                  \
    *(ushort8*)(&LDS[(dstByte) + (unsigned)w * 1024u + (unsigned)l * 16u]) = u; }

  // ---- prologue: fill the pipeline (tiles 0..2 in regs, tile 0 into LDS) ----
  ISSUE_A(0, 0);
  ISSUE_W1(0, 0);
  ISSUE_W1(1, 1);
  ISSUE_W1(2, 2);
  CVT_W1(0, R1 + 0u * 8192u);
  __syncthreads();

  f32x4 acc1[4][8];
#pragma unroll
  for (int mi = 0; mi < 4; ++mi)
#pragma unroll
    for (int n = 0; n < 8; ++n) acc1[mi][n] = f32x4{0.f, 0.f, 0.f, 0.f};

  // ---- phase A: layer 1, K-loop over D in 16 steps of 32, pipeline depth 3 ----
#pragma unroll
  for (int s = 0; s < 16; ++s) {
    // issue prefetches first (FIFO: newer than anything we wait on this step)
    if (s + 1 < 16) ISSUE_A(s + 1, (s + 1) & 1);
    if (s + 3 < 16) ISSUE_W1(s + 3, (s + 3) & 3);

    // compute on tile s: b-frags from ring, a-frags from regs (waits a(s) only,
    // leaving w1(s+2), w1(s+3), a(s+1) in flight)
#pragma unroll
    for (int n = 0; n < 8; ++n) {
      const bf16x8 b = *(const bf16x8*)(&LDS[R1 + (unsigned)(s & 3) * 8192u + (unsigned)n * 1024u + (unsigned)l * 16u]);
#pragma unroll
      for (int mi = 0; mi < 4; ++mi)
        acc1[mi][n] = __builtin_amdgcn_mfma_f32_16x16x32_bf16(aS[s & 1][mi], b, acc1[mi][n], 0, 0, 0);
    }

    // convert + LDS-write tile s+1 (its loads were issued at step s-2)
    if (s < 15) CVT_W1((s + 1) & 3, R1 + (unsigned)((s + 1) & 3) * 8192u);

    // W2 staging: tile t issued at step t (t<4), converted at step t+2
    if (s >= 2 && s < 6) CVT_W2(s & 1, W2BASE + (unsigned)(s - 2) * 8192u);
    if (s < 4) ISSUE_W2(s, s & 1);

    __syncthreads();
  }

#undef ISSUE_W1
#undef ISSUE_W2
#undef ISSUE_A
#undef CVT_W1
#undef CVT_W2

  // per-lane biases / head weights (fp32, kept exact)
  float b1v[8], b2v[8], w3v[8];
#pragma unroll
  for (int n = 0; n < 8; ++n) {
    b1v[n] = b1[v * HH + n * 16 + ll];
    b2v[n] = b2[v * HH + n * 16 + ll];
    w3v[n] = W3[v * HH + n * 16 + ll];
  }
  const float b3v = b3[v];

  const unsigned slot = H1BASE + (unsigned)w * 4096u;  // wave-private 16x128 bf16

  // ---- phase B: layers 2+3, per 16-row block (no cross-wave sync needed) ----
#pragma unroll
  for (int mi = 0; mi < 4; ++mi) {
    // write h1 block, XOR-swizzle rows so layer-2 A-frag reads are conflict-free
#pragma unroll
    for (int n = 0; n < 8; ++n) {
#pragma unroll
      for (int r = 0; r < 4; ++r) {
        const int tl = lg * 4 + r;
        float hv = acc1[mi][n][r] + b1v[n];
        hv = fmaxf(hv, 0.f);
        const int h = n * 16 + ll;
        const unsigned byte = slot + (unsigned)tl * 256u + (unsigned)((h * 2) ^ ((tl & 7) << 4));
        *(unsigned short*)(&LDS[byte]) = f2bf(hv);
      }
    }
    // layer 2: [16t x 128h] = h1 @ W2
    f32x4 acc2[8];
#pragma unroll
    for (int n = 0; n < 8; ++n) acc2[n] = f32x4{0.f, 0.f, 0.f, 0.f};
#pragma unroll
    for (int ki = 0; ki < 4; ++ki) {
      const int k0 = ki * 32 + lg * 8;
      const unsigned abyte = slot + (unsigned)ll * 256u + (unsigned)((k0 * 2) ^ ((ll & 7) << 4));
      const bf16x8 a2 = *(const bf16x8*)(&LDS[abyte]);
#pragma unroll
      for (int n = 0; n < 8; ++n) {
        const bf16x8 bw = *(const bf16x8*)(&LDS[W2BASE + (unsigned)ki * 8192u + (unsigned)n * 1024u + (unsigned)l * 16u]);
        acc2[n] = __builtin_amdgcn_mfma_f32_16x16x32_bf16(a2, bw, acc2[n], 0, 0, 0);
      }
    }
    // layer 3 (fp32): relu(acc2+b2) . w3, 16-lane butterfly reduce, lane0 writes
#pragma unroll
    for (int r = 0; r < 4; ++r) {
      float p = 0.f;
#pragma unroll
      for (int n = 0; n < 8; ++n)
        p += fmaxf(acc2[n][r] + b2v[n], 0.f) * w3v[n];
      p += __shfl_xor(p, 1);
      p += __shfl_xor(p, 2);
      p += __shfl_xor(p, 4);
      p += __shfl_xor(p, 8);
      if (ll == 0) {
        const int t = w * 64 + mi * 16 + lg * 4 + r;
        out[t * VV + v] = p + b3v;
      }
    }
  }
}

extern "C" void kernel_launch(void* const* d_in, const int* in_sizes, int n_in,
                              void* d_out, int out_size, void* d_ws, size_t ws_size,
                              hipStream_t stream) {
  const float* X  = (const float*)d_in[0];
  const float* W1 = (const float*)d_in[1];
  const float* b1 = (const float*)d_in[2];
  const float* W2 = (const float*)d_in[3];
  const float* b2 = (const float*)d_in[4];
  const float* W3 = (const float*)d_in[5];
  const float* b3 = (const float*)d_in[6];
  float* out = (float*)d_out;

  unsigned short* Xb = (unsigned short*)d_ws;   // 512 KiB bf16 X

  cvt_x_kernel<<<256, 256, 0, stream>>>(X, Xb);
  voxel_mlp_kernel<<<VV, 512, 0, stream>>>(Xb, W1, b1, W2, b2, W3, b3, out);
}